// Round 17
// baseline (173.387 us; speedup 1.0000x reference)
//
#include <hip/hip_runtime.h>

typedef unsigned short u16;
typedef unsigned int u32;
typedef __attribute__((ext_vector_type(8))) short bf16x8;
typedef __attribute__((ext_vector_type(4))) float f32x4;
typedef __attribute__((ext_vector_type(2))) float f32x2;

#define DEVI static __device__ __forceinline__

DEVI float bf2f(u16 u){ u32 x = ((u32)u) << 16; float f; __builtin_memcpy(&f, &x, 4); return f; }
DEVI u16 f2bf(float f){ u32 x; __builtin_memcpy(&x, &f, 4); u32 r = x + 0x7FFFu + ((x >> 16) & 1u); return (u16)(r >> 16); }
DEVI u32 pk2(float a, float b){ return ((u32)f2bf(b) << 16) | (u32)f2bf(a); }

DEVI f32x4 mfma16(bf16x8 a, bf16x8 b, f32x4 c){
  return __builtin_amdgcn_mfma_f32_16x16x32_bf16(a, b, c, 0, 0, 0);
}

typedef __attribute__((address_space(3))) u32* lds_ptr_t;
typedef const __attribute__((address_space(1))) u32* gbl_ptr_t;
DEVI void gload16(const void* g, const void* l){
  __builtin_amdgcn_global_load_lds((gbl_ptr_t)(unsigned long long)g,
                                   (lds_ptr_t)(unsigned long long)l,
                                   16, 0, 0);
}

// ---------------- prep: X->bf16 (blocks 0..4095) + weight transposes/bias (4096..5254) ----------------
__global__ void prep_kernel(const float* __restrict__ X, u16* __restrict__ Xb,
                            const float* __restrict__ Wq, const float* __restrict__ Wk,
                            const float* __restrict__ Wv, const float* __restrict__ Wd,
                            const float* __restrict__ Wo,
                            const float* __restrict__ Wqb, const float* __restrict__ Wkb,
                            const float* __restrict__ Wvb, const float* __restrict__ Wdb,
                            u16* __restrict__ WT, float* __restrict__ biasAll)
{
  __shared__ __align__(16) char pbuf[4224];
  if (blockIdx.x < 4096){
    int i = blockIdx.x * 256 + threadIdx.x;
    const f32x4* p = (const f32x4*)X;
    f32x4 a = p[(size_t)i*2], c = p[(size_t)i*2 + 1];
    bf16x8 v;
    v[0]=(short)f2bf(a[0]); v[1]=(short)f2bf(a[1]); v[2]=(short)f2bf(a[2]); v[3]=(short)f2bf(a[3]);
    v[4]=(short)f2bf(c[0]); v[5]=(short)f2bf(c[1]); v[6]=(short)f2bf(c[2]); v[7]=(short)f2bf(c[3]);
    *(bf16x8*)(Xb + (size_t)i*8) = v;
    return;
  }
  int id = blockIdx.x - 4096;
  if (id >= 1152){
    int c = (id - 1152) * 256 + threadIdx.x;
    float v = (c < 512) ? Wqb[c] : (c < 1024) ? Wkb[c-512] : (c < 1536) ? Wvb[c-1024] : Wdb[c-1536];
    biasAll[c] = v;
    return;
  }
  const float* W; int RO, N, local;
  if      (id < 256){ W = Wq; RO = 0;    N = 512; local = id; }
  else if (id < 512){ W = Wk; RO = 512;  N = 512; local = id - 256; }
  else if (id < 768){ W = Wv; RO = 1024; N = 512; local = id - 512; }
  else if (id < 896){ W = Wd; RO = 1536; N = 256; local = id - 768; }
  else              { W = Wo; RO = 1792; N = 512; local = id - 896; }
  int ntiles = N >> 5;
  int n0 = (local & (ntiles - 1)) * 32, k0 = (local / ntiles) * 32;
  float (*tile)[33] = (float(*)[33])pbuf;
  int tx = threadIdx.x & 31, ty = threadIdx.x >> 5;
  #pragma unroll
  for (int i = 0; i < 32; i += 8)
    tile[ty + i][tx] = W[(size_t)(k0 + ty + i) * N + n0 + tx];
  __syncthreads();
  #pragma unroll
  for (int i = 0; i < 32; i += 8)
    WT[(size_t)(RO + n0 + ty + i) * 512 + k0 + tx] = f2bf(tile[tx][ty + i]);
}

// ---------------- 128x128 pipelined GEMM (BK=64, 2-slot ring, 2 blocks/CU, persistent) ----------------
// MODE 0: A=Xb, B=WT[0,1792): bx 0-3 Q, 4-7 K(preLN), 8-11 V(preLN + row stats), 12-13 hs
//         grid 896 (2 chunks/block, dynamic backfill -> small tail)
// MODE 1: A=Cbp, B=WT[1792,2304): f32 out + bias; grid 512 (1 chunk/block)
template<int MODE>
__global__ __launch_bounds__(256, 2) void gemmP(
    const u16* __restrict__ Abase, const u16* __restrict__ WT, const float* __restrict__ biasAll,
    u16* __restrict__ Qb, u16* __restrict__ Kb, u16* __restrict__ Vb,
    float* __restrict__ hsf, float* __restrict__ cmx, float* __restrict__ csm,
    float* __restrict__ pstatV, float* __restrict__ Cf)
{
  __shared__ __align__(16) u16 smem[32768];   // 64 KB: A[2][8192] | B[2][8192]
  const int t = threadIdx.x, lane = t & 63, w = t >> 6;
  const int wm = w >> 1, wn = w & 1;
  const int lrow = lane & 15, lk = lane >> 4;
  const u16* Bbase = (MODE == 0) ? WT : (WT + (size_t)1792*512);
  const int srow = w*32 + (lane >> 3);
  const int scol = ((lane & 7) ^ (lane >> 3)) * 8;
  const int swz = (lrow & 7);
  const int NCH = (MODE == 0) ? 1792 : 512;
  const f32x4 fz = {0.f,0.f,0.f,0.f};

  for (int ch = blockIdx.x; ch < NCH; ch += gridDim.x){
    int by, bx;
    {
      int xcd = ch & 7, c = ch >> 3;
      if (MODE == 0){ by = xcd*16 + c/14;   bx = c % 14; }
      else          { by = xcd*16 + (c>>2); bx = c & 3; }
    }
    const int m0 = by*128, n0 = bx*128;
    const u16* sA = Abase + (size_t)(m0 + srow)*512 + scol;
    const u16* sB = Bbase + (size_t)(n0 + srow)*512 + scol;

    f32x4 acc[4][4];
    #pragma unroll
    for (int i = 0; i < 4; i++)
      #pragma unroll
      for (int j = 0; j < 4; j++) acc[i][j] = fz;

    auto stage = [&](int tt){
      int slot = tt & 1;
      #pragma unroll
      for (int i = 0; i < 4; i++){
        gload16(sA + tt*64 + (size_t)i*4096, smem + slot*8192 + (w*4 + i)*512);
        gload16(sB + tt*64 + (size_t)i*4096, smem + 16384 + slot*8192 + (w*4 + i)*512);
      }
    };

    stage(0);
    stage(1);

    #pragma unroll
    for (int tt = 0; tt < 8; tt++){
      if (tt < 7) asm volatile("s_waitcnt vmcnt(8)" ::: "memory");   // tile tt landed
      else        asm volatile("s_waitcnt vmcnt(0)" ::: "memory");
      __builtin_amdgcn_s_barrier();
      const u16* aS = smem + (tt & 1)*8192;
      const u16* bS = smem + 16384 + (tt & 1)*8192;
      #pragma unroll
      for (int ks = 0; ks < 2; ks++){
        bf16x8 af[4], bfv[4];
        #pragma unroll
        for (int mi = 0; mi < 4; mi++){
          int r = wm*64 + mi*16 + lrow;
          af[mi] = *(const bf16x8*)(aS + (r*8 + ((ks*4 + lk) ^ swz))*8);
        }
        #pragma unroll
        for (int ni = 0; ni < 4; ni++){
          int r = wn*64 + ni*16 + lrow;
          bfv[ni] = *(const bf16x8*)(bS + (r*8 + ((ks*4 + lk) ^ swz))*8);
        }
        #pragma unroll
        for (int mi = 0; mi < 4; mi++)
          #pragma unroll
          for (int ni = 0; ni < 4; ni++)
            acc[mi][ni] = mfma16(bfv[ni], af[mi], acc[mi][ni]);   // C^T frags
      }
      __builtin_amdgcn_s_barrier();       // all waves done reading slot tt&1
      if (tt + 2 < 8) stage(tt + 2);      // now safe to overwrite it
    }

    // ---------------- epilogue (C^T: thread holds 4 consecutive output cols) ----------------
    if (MODE == 1){
      #pragma unroll
      for (int mi = 0; mi < 4; mi++){
        int grow = m0 + wm*64 + mi*16 + lrow;
        #pragma unroll
        for (int ni = 0; ni < 4; ni++){
          int gcol0 = n0 + wn*64 + ni*16 + lk*4;
          f32x4 bv4 = *(const f32x4*)(biasAll + gcol0);
          f32x4 vv;
          #pragma unroll
          for (int rr = 0; rr < 4; rr++) vv[rr] = acc[mi][ni][rr] + bv4[rr];
          *(f32x4*)(Cf + (size_t)grow*512 + gcol0) = vv;
        }
      }
      continue;
    }

    if (bx < 12){
      const int sel = bx >> 2;
      u16* dst = (sel == 0) ? Qb : (sel == 1) ? Kb : Vb;
      const float scale = (sel == 0) ? 0.125f : 1.0f;
      f32x4 bv4s[4];
      #pragma unroll
      for (int ni = 0; ni < 4; ni++)
        bv4s[ni] = *(const f32x4*)(biasAll + n0 + wn*64 + ni*16 + lk*4);
      #pragma unroll
      for (int mi = 0; mi < 4; mi++){
        int grow = m0 + wm*64 + mi*16 + lrow;
        int b = grow >> 13, s = grow & 8191;
        #pragma unroll
        for (int ni = 0; ni < 4; ni++){
          int gcol0 = n0 + wn*64 + ni*16 + lk*4;
          int lcol0 = gcol0 & 511, hh = lcol0 >> 6, dd0 = lcol0 & 63;
          float v0 = (acc[mi][ni][0] + bv4s[ni][0]) * scale;
          float v1 = (acc[mi][ni][1] + bv4s[ni][1]) * scale;
          float v2 = (acc[mi][ni][2] + bv4s[ni][2]) * scale;
          float v3 = (acc[mi][ni][3] + bv4s[ni][3]) * scale;
          u32* p = (u32*)(dst + (((size_t)(b*8 + hh))*8192 + s)*64 + dd0);
          p[0] = pk2(v0, v1);
          p[1] = pk2(v2, v3);
        }
      }
      if (sel == 2){
        float* vst = (float*)smem;      // [128][4] : per-wn {sum,sq}
        __syncthreads();
        #pragma unroll
        for (int mi = 0; mi < 4; mi++){
          float s = 0.f, q = 0.f;
          #pragma unroll
          for (int ni = 0; ni < 4; ni++)
            #pragma unroll
            for (int rr = 0; rr < 4; rr++){
              float v = acc[mi][ni][rr] + bv4s[ni][rr];
              s += v; q += v*v;
            }
          s += __shfl_xor(s, 16); q += __shfl_xor(q, 16);
          s += __shfl_xor(s, 32); q += __shfl_xor(q, 32);
          if (lk == 0){
            int rloc = wm*64 + mi*16 + lrow;
            vst[rloc*4 + wn*2]     = s;
            vst[rloc*4 + wn*2 + 1] = q;
          }
        }
        __syncthreads();
        if (t < 128){
          float s = vst[t*4+0] + vst[t*4+2];
          float q = vst[t*4+1] + vst[t*4+3];
          pstatV[(size_t)(m0 + t)*8 + (bx - 8)*2]     = s;
          pstatV[(size_t)(m0 + t)*8 + (bx - 8)*2 + 1] = q;
        }
      }
    } else {
      // hs: f32x4 stores + per-128-row column softmax partials (one chunk per block)
      float* pm = (float*)smem;          // [2][128]
      float* ps = pm + 256;
      __syncthreads();
      #pragma unroll
      for (int ni = 0; ni < 4; ni++){
        int gcol0 = n0 + wn*64 + ni*16 + lk*4;
        int c0 = gcol0 - 1536;
        f32x4 bv4 = *(const f32x4*)(biasAll + gcol0);
        float mx[4], sm[4];
        #pragma unroll
        for (int rr = 0; rr < 4; rr++){ mx[rr] = -1e30f; sm[rr] = 0.f; }
        #pragma unroll
        for (int mi = 0; mi < 4; mi++){
          int grow = m0 + wm*64 + mi*16 + lrow;
          f32x4 v;
          #pragma unroll
          for (int rr = 0; rr < 4; rr++){
            v[rr] = acc[mi][ni][rr] + bv4[rr];
            float nm = fmaxf(mx[rr], v[rr]);
            sm[rr] = sm[rr]*__expf(mx[rr] - nm) + __expf(v[rr] - nm);
            mx[rr] = nm;
          }
          *(f32x4*)(hsf + (size_t)grow*256 + c0) = v;
        }
        #pragma unroll
        for (int rr = 0; rr < 4; rr++){
          #pragma unroll
          for (int d2 = 1; d2 < 16; d2 <<= 1){
            float om = __shfl_xor(mx[rr], d2), os = __shfl_xor(sm[rr], d2);
            float nm = fmaxf(mx[rr], om);
            sm[rr] = sm[rr]*__expf(mx[rr] - nm) + os*__expf(om - nm);
            mx[rr] = nm;
          }
        }
        if (lrow == 0){
          int cl = wn*64 + ni*16 + lk*4;
          f32x4 m4 = {mx[0], mx[1], mx[2], mx[3]};
          f32x4 s4 = {sm[0], sm[1], sm[2], sm[3]};
          *(f32x4*)(pm + wm*128 + cl) = m4;
          *(f32x4*)(ps + wm*128 + cl) = s4;
        }
      }
      __syncthreads();
      if (t < 128){
        float ma = pm[t], mb = pm[128 + t];
        float nm = fmaxf(ma, mb);
        float s = ps[t]*__expf(ma - nm) + ps[128 + t]*__expf(mb - nm);
        int b = m0 >> 13, chunk = (m0 & 8191) >> 7;
        int c = (n0 - 1536) + t;
        cmx[((size_t)b*64 + chunk)*256 + c] = nm;
        csm[((size_t)b*64 + chunk)*256 + c] = s;
      }
    }
    __syncthreads();   // protect smem/LDS ring before next chunk's staging
  }
}

// ---------------- mid: K LN stats (0..4095) + V LN/transpose (4096..6143) + smax comb (6144..6145) ----------------
__global__ __launch_bounds__(256) void mid_kernel(
    const u16* __restrict__ Kb, float* __restrict__ kstat,
    const u16* __restrict__ Vb, const float* __restrict__ pstatV,
    const float* __restrict__ gg, const float* __restrict__ bb, u16* __restrict__ VbT,
    const float* __restrict__ cmax, const float* __restrict__ csum,
    float* __restrict__ gmax, float* __restrict__ gsum)
{
  __shared__ __align__(16) char mbuf[9216];
  const int bid = blockIdx.x;
  if (bid < 4096){
    const int lane = threadIdx.x & 63, w = threadIdx.x >> 6;
    const int row = bid * 4 + w;
    const int b = row >> 13, si = row & 8191;
    const int hh = lane >> 3, d = (lane & 7) * 8;
    const u16* p = Kb + (((size_t)(b*8 + hh))*8192 + si)*64 + d;
    bf16x8 raw = *(const bf16x8*)p;
    float x[8];
    #pragma unroll
    for (int j = 0; j < 8; j++) x[j] = bf2f((u16)raw[j]);
    float s = 0.f, q = 0.f;
    #pragma unroll
    for (int j = 0; j < 8; j++){ s += x[j]; q += x[j]*x[j]; }
    #pragma unroll
    for (int d2 = 1; d2 < 64; d2 <<= 1){ s += __shfl_xor(s, d2); q += __shfl_xor(q, d2); }
    float mean = s * (1.f/512.f);
    float var  = q * (1.f/512.f) - mean*mean;
    float rstd = rsqrtf(var + 1e-5f);
    if (lane == 0){
      kstat[(size_t)row*2]     = mean;
      kstat[(size_t)row*2 + 1] = rstd;
    }
    return;
  }
  if (bid < 6144){
    int id2 = bid - 4096;
    const int st = id2 & 127, bh = id2 >> 7;
    const int b = bh >> 3, h = bh & 7;
    const int t = threadIdx.x;
    u16 (*tile)[72] = (u16(*)[72])mbuf;
    {
      int row = t >> 2, cc = (t & 3) * 16;
      int grow = b*8192 + st*64 + row;
      f32x4 p0 = *(const f32x4*)(pstatV + (size_t)grow*8);
      f32x4 p1 = *(const f32x4*)(pstatV + (size_t)grow*8 + 4);
      float mean = (p0[0]+p0[2]+p1[0]+p1[2]) * (1.f/512.f);
      float msq  = (p0[1]+p0[3]+p1[1]+p1[3]) * (1.f/512.f);
      float rstd = rsqrtf(msq - mean*mean + 1e-5f);
      const u16* src = Vb + ((size_t)bh*8192 + st*64 + row)*64 + cc;
      bf16x8 v0 = *(const bf16x8*)src, v1 = *(const bf16x8*)(src + 8);
      #pragma unroll
      for (int j = 0; j < 8; j++){
        int c = h*64 + cc + j;
        tile[row][cc + j]     = f2bf((bf2f((u16)v0[j]) - mean)*rstd*gg[c] + bb[c]);
        int c2 = c + 8;
        tile[row][cc + 8 + j] = f2bf((bf2f((u16)v1[j]) - mean)*rstd*gg[c2] + bb[c2]);
      }
    }
    __syncthreads();
    {
      int d = t >> 2, sc4 = (t & 3) * 16;
      bf16x8 o0, o1;
      #pragma unroll
      for (int i = 0; i < 8; i++) o0[i] = (short)tile[sc4 + i][d];
      #pragma unroll
      for (int i = 0; i < 8; i++) o1[i] = (short)tile[sc4 + 8 + i][d];
      u16* dst = VbT + ((size_t)bh*64 + d)*8192 + st*64 + sc4;
      *(bf16x8*)dst       = o0;
      *(bf16x8*)(dst + 8) = o1;
    }
    return;
  }
  {
    int b = bid - 6144, c = threadIdx.x;
    float m[4], s[4];
    #pragma unroll
    for (int u = 0; u < 4; u++){ m[u] = -1e30f; s[u] = 0.f; }
    for (int ch = 0; ch < 64; ch += 4){
      #pragma unroll
      for (int u = 0; u < 4; u++){
        float cm = cmax[((size_t)b*64 + ch + u)*256 + c];
        float cs = csum[((size_t)b*64 + ch + u)*256 + c];
        float nm = fmaxf(m[u], cm);
        s[u] = s[u]*__expf(m[u] - nm) + cs*__expf(cm - nm);
        m[u] = nm;
      }
    }
    #pragma unroll
    for (int u = 1; u < 4; u++){
      float nm = fmaxf(m[0], m[u]);
      s[0] = s[0]*__expf(m[0]-nm) + s[u]*__expf(m[u]-nm);
      m[0] = nm;
    }
    gmax[b*256 + c] = m[0]; gsum[b*256 + c] = s[0];
  }
}

// ---------------- compressed K_c/V_c partial sums via MFMA (K,V LN'd on the fly) ----------------
__global__ __launch_bounds__(256) void cmp2_kernel(const float* __restrict__ hsf,
    const float* __restrict__ gmax, const float* __restrict__ gsum,
    const u16* __restrict__ Kb, const u16* __restrict__ Vb,
    const float* __restrict__ kstat, const float* __restrict__ pstatV,
    const float* __restrict__ gg, const float* __restrict__ bb,
    float* __restrict__ pK, float* __restrict__ pV)
{
  __shared__ __align__(16) u16 Pt[32*72];
  __shared__ __align__(16) u16 Kt[64*72];
  __shared__ __align__(16) u16 Vt[64*72];
  const int sch = blockIdx.x, bh = blockIdx.y;
  const int b = bh >> 3, h = bh & 7;
  const int t = threadIdx.x, lane = t & 63, w = t >> 6;
  const int lrow = lane & 15, lk = lane >> 4;
  const int sl = lane;
  float gm[8], gi[8];
  #pragma unroll
  for (int j = 0; j < 8; j++){
    int c = h*32 + w*8 + j;
    gm[j] = gmax[b*256 + c];
    gi[j] = 1.0f / gsum[b*256 + c];
  }
  float glv[16], blv[16];
  #pragma unroll
  for (int j = 0; j < 16; j++){
    int c = h*64 + w*16 + j;
    glv[j] = gg[c]; blv[j] = bb[c];
  }
  const f32x4 fz = {0.f,0.f,0.f,0.f};
  f32x4 aK[2], aV[2];
  aK[0]=fz; aK[1]=fz; aV[0]=fz; aV[1]=fz;

  for (int tile = 0; tile < 4; ++tile){
    int s0 = sch*256 + tile*64;
    int grow = b*8192 + s0 + sl;
    {
      const float* src = hsf + (size_t)grow*256 + h*32 + w*8;
      f32x4 x0 = *(const f32x4*)src, x1 = *(const f32x4*)(src + 4);
      #pragma unroll
      for (int j = 0; j < 4; j++){
        Pt[(w*8 + j)*72 + sl]     = f2bf(__expf(x0[j] - gm[j])   * gi[j]);
        Pt[(w*8 + 4 + j)*72 + sl] = f2bf(__expf(x1[j] - gm[4+j]) * gi[4+j]);
      }
    }
    {
      f32x2 st = *(const f32x2*)(kstat + (size_t)grow*2);
      const u16* ks = Kb + ((size_t)bh*8192 + s0 + sl)*64 + w*16;
      bf16x8 k0 = *(const bf16x8*)ks, k1 = *(const bf16x8*)(ks + 8);
      #pragma unroll
      for (int j = 0; j < 8; j++){
        Kt[(w*16 + j)*72 + sl]     = f2bf((bf2f((u16)k0[j]) - st[0])*st[1]*glv[j]   + blv[j]);
        Kt[(w*16 + 8 + j)*72 + sl] = f2bf((bf2f((u16)k1[j]) - st[0])*st[1]*glv[8+j] + blv[8+j]);
      }
    }
    {
      f32x4 p0 = *(const f32x4*)(pstatV + (size_t)grow*8);
      f32x4 p1 = *(const f32x4*)(pstatV + (size_t)grow*8 + 4);
      float mean = (p0[0]+p0[2]+p1[0]+p1[2]) * (1.f/512.f);
      float msq  = (p0[1]+p0[3]+p1[1]+p1[3]) * (1.f/512.f);
      float rstd = rsqrtf(msq - mean*mean + 1e-5f);
      const u16* vs = Vb + ((size_t)bh*8192 + s0 + sl)*64 + w*16;
      bf16x8 v0 = *(const bf16x8*)vs, v1 = *(const bf16x8*)(vs + 8);
      #pragma unroll
      for (int j = 0; j < 8; j++){
        Vt[(w*16 + j)*72 + sl]     = f2bf((bf2f((u16)v0[j]) - mean)*rstd*glv[j]   + blv[j]);
        Vt[(w*16 + 8 + j)*72 + sl] = f2bf((bf2f((u16)v1[j]) - mean)*rstd*glv[8+j] + blv[8+j]);
      }
    }
    __syncthreads();
    #pragma unroll
    for (int ks = 0; ks < 2; ks++){
      bf16x8 a0 = *(const bf16x8*)(Pt + (lrow)*72      + ks*32 + lk*8);
      bf16x8 a1 = *(const bf16x8*)(Pt + (16 + lrow)*72 + ks*32 + lk*8);
      bf16x8 bK = *(const bf16x8*)(Kt + (w*16 + lrow)*72 + ks*32 + lk*8);
      bf16x8 bV = *(const bf16x8*)(Vt + (w*16 + lrow)*72 + ks*32 + lk*8);
      aK[0] = mfma16(a0, bK, aK[0]);
      aK[1] = mfma16(a1, bK, aK[1]);
      aV[0] = mfma16(a0, bV, aV[0]);
      aV[1] = mfma16(a1, bV, aV[1]);
    }
    __syncthreads();
  }
  size_t base = ((size_t)bh*32 + sch)*2048;
  #pragma unroll
  for (int li = 0; li < 2; li++){
    #pragma unroll
    for (int r = 0; r < 4; r++){
      size_t o = base + (size_t)(li*16 + lk*4 + r)*64 + w*16 + lrow;
      pK[o] = aK[li][r];
      pV[o] = aV[li][r];
    }
  }
}

// ---------------- reduce partials + LN_s -> Kcb [bh][32][64], VcT [bh][64][32] ----------------
__global__ __launch_bounds__(256) void ln_c_kernel(const float* __restrict__ pK, const float* __restrict__ pV,
    const float* __restrict__ gg, const float* __restrict__ bb,
    u16* __restrict__ Kcb, u16* __restrict__ VcT)
{
  __shared__ float red[4][4];
  const int b = blockIdx.x >> 5, l = blockIdx.x & 31;
  const int t = threadIdx.x, lane = t & 63, w = t >> 6;
  float xk[2], xv[2];
  #pragma unroll
  for (int q2 = 0; q2 < 2; q2++){
    int c = t + q2*256;
    int hh = c >> 6, d = c & 63;
    float sk = 0.f, sv = 0.f;
    for (int ch = 0; ch < 32; ch++){
      size_t idx = (((size_t)(b*8 + hh)*32 + ch)*2048) + l*64 + d;
      sk += pK[idx]; sv += pV[idx];
    }
    xk[q2] = sk; xv[q2] = sv;
  }
  float s1 = xk[0]+xk[1], q1 = xk[0]*xk[0]+xk[1]*xk[1];
  float s2 = xv[0]+xv[1], q2s = xv[0]*xv[0]+xv[1]*xv[1];
  #pragma unroll
  for (int d2 = 1; d2 < 64; d2 <<= 1){
    s1 += __shfl_xor(s1, d2); q1 += __shfl_xor(q1, d2);
    s2 += __shfl_xor(s2, d2); q2s += __shfl_xor(q2s, d2);
  }
  if (lane == 0){ red[0][w]=s1; red[1][w]=q1; red[2][w]=s2; red[3][w]=q2s; }
  __syncthreads();
  s1 = red[0][0]+red[0][1]+red[0][2]+red[0][3];
  q1 = red[1][0]+red[1][1]+red[1][2]+red[1][3];
  s2 = red[2][0]+red[2][1]+red[2][2]+red[2][3];
  q2s = red[3][0]+red[3][1]+red[3][2]+red[3][3];
  float mk = s1*(1.f/512.f), vk = q1*(1.f/512.f) - mk*mk, rk = rsqrtf(vk + 1e-5f);
  float mv = s2*(1.f/512.f), vvv = q2s*(1.f/512.f) - mv*mv, rv = rsqrtf(vvv + 1e-5f);
  #pragma unroll
  for (int q2 = 0; q2 < 2; q2++){
    int c = t + q2*256;
    int hh = c >> 6, d = c & 63;
    Kcb[(((size_t)(b*8 + hh))*32 + l)*64 + d] = f2bf((xk[q2]-mk)*rk*gg[c] + bb[c]);
    VcT[(((size_t)(b*8 + hh))*64 + d)*32 + l] = f2bf((xv[q2]-mv)*rv*gg[c] + bb[c]);
  }
}

// ---------------- fused long-short attention per (b,h,g); K LN'd during staging ----------------
// XCD-aware g remap (bijective, 64 % 8 == 0).
__global__ __launch_bounds__(512, 4) void attn2_kernel(
    const u16* __restrict__ Qb, const u16* __restrict__ Kb, const u16* __restrict__ Kcb,
    const u16* __restrict__ VbT, const u16* __restrict__ VcT,
    const float* __restrict__ kstat, const float* __restrict__ lnlg, const float* __restrict__ lnlb,
    u16* __restrict__ Cb)
{
  __shared__ __align__(16) char smem[74752];
  u16* Vt = (u16*)(smem + 36864);
  u16* Pl = (u16*)smem;

  const int g = (blockIdx.x & 7) * 8 + (blockIdx.x >> 3);
  const int h = blockIdx.y, b = blockIdx.z;
  const int bh = b*8 + h;
  const int t = threadIdx.x, lane = t & 63, w = t >> 6;
  const int lrow = lane & 15, lk = lane >> 4;
  const int s0 = g*128 - 64;
  const bf16x8 bz = {0,0,0,0,0,0,0,0};
  const f32x4 fz = {0.f,0.f,0.f,0.f};

  float g8[8], b8[8];
  {
    int kcl = t & 7;
    #pragma unroll
    for (int j = 0; j < 8; j++){
      int c = h*64 + kcl*8 + j;
      g8[j] = lnlg[c]; b8[j] = lnlb[c];
    }
  }

  #pragma unroll
  for (int it = 0; it < 5; it++){
    int idx = it*512 + t;
    if (idx < 2304){
      int row = idx >> 3, kc = idx & 7;
      bf16x8 v = bz;
      if (row < 256){
        int sk = s0 + row;
        if (sk >= 0 && sk < 8192){
          v = *(const bf16x8*)(Kb + ((size_t)bh*8192 + sk)*64 + kc*8);
          f32x2 st = *(const f32x2*)(kstat + (size_t)(b*8192 + sk)*2);
          #pragma unroll
          for (int j = 0; j < 8; j++)
            v[j] = (short)f2bf((bf2f((u16)v[j]) - st[0])*st[1]*g8[j] + b8[j]);
        }
      } else {
        v = *(const bf16x8*)(Kcb + ((size_t)bh*32 + (row - 256))*64 + kc*8);
      }
      int off = row*128 + kc*16; off ^= (row & 7) << 4;
      *(bf16x8*)(smem + off) = v;
    }
  }
  #pragma unroll
  for (int it = 0; it < 4; it++){
    int idx = it*512 + t;
    int d = idx >> 5, cc = idx & 31;
    int sk = s0 + cc*8;
    bf16x8 v = bz;
    if (sk >= 0 && sk < 8192) v = *(const bf16x8*)(VbT + ((size_t)bh*64 + d)*8192 + sk);
    *(bf16x8*)(Vt + d*296 + cc*8) = v;
  }
  if (t < 256){
    int d = t >> 2, cc = t & 3;
    bf16x8 v = *(const bf16x8*)(VcT + ((size_t)bh*64 + d)*32 + cc*8);
    *(bf16x8*)(Vt + d*296 + 256 + cc*8) = v;
  }
  bf16x8 qf[2];
  #pragma unroll
  for (int ks = 0; ks < 2; ks++)
    qf[ks] = *(const bf16x8*)(Qb + ((size_t)bh*8192 + g*128 + w*16 + lrow)*64 + ks*32 + lk*8);

  __syncthreads();

  f32x4 sc[18];
  #pragma unroll
  for (int j = 0; j < 18; j++) sc[j] = fz;
  __builtin_amdgcn_s_setprio(1);
  #pragma unroll
  for (int j = 0; j < 18; j++){
    int row = j*16 + lrow;
    #pragma unroll
    for (int ks = 0; ks < 2; ks++){
      int off = row*128 + ks*64 + lk*16; off ^= (row & 7) << 4;
      bf16x8 kf = *(const bf16x8*)(smem + off);
      sc[j] = mfma16(kf, qf[ks], sc[j]);
    }
  }
  __builtin_amdgcn_s_setprio(0);

  #pragma unroll
  for (int j = 0; j < 16; j++){
    int sb = s0 + j*16 + lk*4;
    if (sb < 0 || sb >= 8192){
      sc[j][0] = -1e30f; sc[j][1] = -1e30f; sc[j][2] = -1e30f; sc[j][3] = -1e30f;
    }
  }

  float m = -1e30f;
  #pragma unroll
  for (int j = 0; j < 18; j++)
    m = fmaxf(m, fmaxf(fmaxf(sc[j][0], sc[j][1]), fmaxf(sc[j][2], sc[j][3])));
  m = fmaxf(m, __shfl_xor(m, 16));
  m = fmaxf(m, __shfl_xor(m, 32));
  float ssum = 0.f;
  #pragma unroll
  for (int j = 0; j < 18; j++){
    #pragma unroll
    for (int r = 0; r < 4; r++){
      float e = __expf(sc[j][r] - m);
      sc[j][r] = e; ssum += e;
    }
  }
  ssum += __shfl_xor(ssum, 16);
  ssum += __shfl_xor(ssum, 32);
  float inv = 1.0f / ssum;

  f32x4 ao[4];
  #pragma unroll
  for (int nj = 0; nj < 4; nj++) ao[nj] = fz;
  const int prow = w*16 + lrow;

  #pragma unroll
  for (int c = 0; c < 3; c++){
    __syncthreads();
    #pragma unroll
    for (int jj = 0; jj < 6; jj++){
      int j = c*6 + jj;
      u32* dst = (u32*)(Pl + prow*104 + jj*16 + lk*4);
      dst[0] = pk2(sc[j][0], sc[j][1]);
      dst[1] = pk2(sc[j][2], sc[j][3]);
    }
    __syncthreads();
    __builtin_amdgcn_s_setprio(1);
    #pragma unroll
    for (int ksl = 0; ksl < 3; ksl++){
      bf16x8 pb = *(const bf16x8*)(Pl + prow*104 + ksl*32 + lk*8);
      #pragma unroll
      for (int nj = 0; nj < 4; nj++){
        bf16x8 av = *(const bf16x8*)(Vt + (nj*16 + lrow)*296 + c*96 + ksl*32 + lk*8);
        ao[nj] = mfma16(av, pb, ao[nj]);
      }
    }
    __builtin_amdgcn_s_setprio(0);
  }

  const int qglob = g*128 + w*16 + lrow;
  #pragma unroll
  for (int nj = 0; nj < 4; nj++){
    u32* dst = (u32*)(Cb + ((size_t)b*8192 + qglob)*512 + h*64 + nj*16 + lk*4);
    dst[0] = pk2(ao[nj][0]*inv, ao[nj][1]*inv);
    dst[1] = pk2(ao[nj][2]*inv, ao[nj][3]*inv);
  }
}

// ---------------- workspace layout ----------------
constexpr size_t OFF_XB   = 0;
constexpr size_t OFF_WT   = OFF_XB  + 16777216;
constexpr size_t OFF_QB   = OFF_WT  + 2359296;
constexpr size_t OFF_KB   = OFF_QB  + 16777216;
constexpr size_t OFF_VB   = OFF_KB  + 16777216;
constexpr size_t OFF_CB   = OFF_VB  + 16777216;
constexpr size_t OFF_VBT  = OFF_CB  + 16777216;
constexpr size_t OFF_HSF  = OFF_VBT + 16777216;
constexpr size_t OFF_CMX  = OFF_HSF + 16777216;
constexpr size_t OFF_CSM  = OFF_CMX + 131072;
constexpr size_t OFF_GMX  = OFF_CSM + 131072;
constexpr size_t OFF_GSM  = OFF_GMX + 2048;
constexpr size_t OFF_PK   = OFF_GSM + 2048;
constexpr size_t OFF_PV   = OFF_PK  + 4194304;
constexpr size_t OFF_KCB  = OFF_PV  + 4194304;
constexpr size_t OFF_VCT  = OFF_KCB + 65536;
constexpr size_t OFF_BIAS = OFF_VCT + 65536;
constexpr size_t OFF_PSV  = OFF_BIAS + 8192;          // 16384*8*4 = 524288
constexpr size_t OFF_KST  = OFF_PSV + 524288;         // 16384*2*4 = 131072

extern "C" void kernel_launch(void* const* d_in, const int* in_sizes, int n_in,
                              void* d_out, int out_size, void* d_ws, size_t ws_size,
                              hipStream_t stream)
{
  const float* X    = (const float*)d_in[0];
  const float* Wq   = (const float*)d_in[2];
  const float* Wqb  = (const float*)d_in[3];
  const float* Wk   = (const float*)d_in[4];
  const float* Wkb  = (const float*)d_in[5];
  const float* Wv   = (const float*)d_in[6];
  const float* Wvb  = (const float*)d_in[7];
  const float* Wo   = (const float*)d_in[8];
  const float* Wob  = (const float*)d_in[9];
  const float* lnlg = (const float*)d_in[10];
  const float* lnlb = (const float*)d_in[11];
  const float* lnsg = (const float*)d_in[12];
  const float* lnsb = (const float*)d_in[13];
  const float* Wd   = (const float*)d_in[14];
  const float* Wdb  = (const float*)d_in[15];
  float* out = (float*)d_out;

  char* ws = (char*)d_ws;
  u16*   Xb   = (u16*)(ws + OFF_XB);
  u16*   WT   = (u16*)(ws + OFF_WT);
  u16*   Qb   = (u16*)(ws + OFF_QB);
  u16*   Kb   = (u16*)(ws + OFF_KB);
  u16*   Vb   = (u16*)(ws + OFF_VB);
  u16*   Cbp  = (u16*)(ws + OFF_CB);
  u16*   VbT  = (u16*)(ws + OFF_VBT);
  float* hsf  = (float*)(ws + OFF_HSF);
  float* cmx  = (float*)(ws + OFF_CMX);
  float* csm  = (float*)(ws + OFF_CSM);
  float* gmx  = (float*)(ws + OFF_GMX);
  float* gsm  = (float*)(ws + OFF_GSM);
  float* pK   = (float*)(ws + OFF_PK);
  float* pV   = (float*)(ws + OFF_PV);
  u16*   Kcb  = (u16*)(ws + OFF_KCB);
  u16*   VcT  = (u16*)(ws + OFF_VCT);
  float* biasAll = (float*)(ws + OFF_BIAS);
  float* pstatV  = (float*)(ws + OFF_PSV);
  float* kstat   = (float*)(ws + OFF_KST);

  prep_kernel<<<dim3(5255), dim3(256), 0, stream>>>(X, Xb, Wq, Wk, Wv, Wd, Wo,
                                                    Wqb, Wkb, Wvb, Wdb, WT, biasAll);

  gemmP<0><<<dim3(896), dim3(256), 0, stream>>>(Xb, WT, biasAll, Qb, Kb, Vb,
                                                hsf, cmx, csm, pstatV, nullptr);

  mid_kernel<<<dim3(6146), dim3(256), 0, stream>>>(Kb, kstat, Vb, pstatV, lnlg, lnlb, VbT,
                                                   cmx, csm, gmx, gsm);

  cmp2_kernel<<<dim3(32,16), dim3(256), 0, stream>>>(hsf, gmx, gsm, Kb, Vb, kstat, pstatV,
                                                     lnlg, lnlb, pK, pV);
  ln_c_kernel<<<dim3(64), dim3(256), 0, stream>>>(pK, pV, lnsg, lnsb, Kcb, VcT);

  attn2_kernel<<<dim3(64,8,2), dim3(512), 0, stream>>>(Qb, Kb, Kcb, VbT, VcT,
                                                       kstat, lnlg, lnlb, Cbp);

  gemmP<1><<<dim3(512), dim3(256), 0, stream>>>(Cbp, WT, Wob, nullptr, nullptr, nullptr,
                                                nullptr, nullptr, nullptr, nullptr, out);
}

// Round 18
// 163.828 us; speedup vs baseline: 1.0583x; 1.0583x over previous
//
#include <hip/hip_runtime.h>

typedef unsigned short u16;
typedef unsigned int u32;
typedef __attribute__((ext_vector_type(8))) short bf16x8;
typedef __attribute__((ext_vector_type(4))) float f32x4;
typedef __attribute__((ext_vector_type(2))) float f32x2;

#define DEVI static __device__ __forceinline__

DEVI float bf2f(u16 u){ u32 x = ((u32)u) << 16; float f; __builtin_memcpy(&f, &x, 4); return f; }
DEVI u16 f2bf(float f){ u32 x; __builtin_memcpy(&x, &f, 4); u32 r = x + 0x7FFFu + ((x >> 16) & 1u); return (u16)(r >> 16); }
DEVI u32 pk2(float a, float b){ return ((u32)f2bf(b) << 16) | (u32)f2bf(a); }

DEVI f32x4 mfma16(bf16x8 a, bf16x8 b, f32x4 c){
  return __builtin_amdgcn_mfma_f32_16x16x32_bf16(a, b, c, 0, 0, 0);
}

typedef __attribute__((address_space(3))) u32* lds_ptr_t;
typedef const __attribute__((address_space(1))) u32* gbl_ptr_t;
DEVI void gload16(const void* g, const void* l){
  __builtin_amdgcn_global_load_lds((gbl_ptr_t)(unsigned long long)g,
                                   (lds_ptr_t)(unsigned long long)l,
                                   16, 0, 0);
}

// ---------------- prep: X->bf16 (blocks 0..4095) + weight transposes/bias (4096..5254) ----------------
__global__ void prep_kernel(const float* __restrict__ X, u16* __restrict__ Xb,
                            const float* __restrict__ Wq, const float* __restrict__ Wk,
                            const float* __restrict__ Wv, const float* __restrict__ Wd,
                            const float* __restrict__ Wo,
                            const float* __restrict__ Wqb, const float* __restrict__ Wkb,
                            const float* __restrict__ Wvb, const float* __restrict__ Wdb,
                            u16* __restrict__ WT, float* __restrict__ biasAll)
{
  __shared__ __align__(16) char pbuf[4224];
  if (blockIdx.x < 4096){
    int i = blockIdx.x * 256 + threadIdx.x;
    const f32x4* p = (const f32x4*)X;
    f32x4 a = p[(size_t)i*2], c = p[(size_t)i*2 + 1];
    bf16x8 v;
    v[0]=(short)f2bf(a[0]); v[1]=(short)f2bf(a[1]); v[2]=(short)f2bf(a[2]); v[3]=(short)f2bf(a[3]);
    v[4]=(short)f2bf(c[0]); v[5]=(short)f2bf(c[1]); v[6]=(short)f2bf(c[2]); v[7]=(short)f2bf(c[3]);
    *(bf16x8*)(Xb + (size_t)i*8) = v;
    return;
  }
  int id = blockIdx.x - 4096;
  if (id >= 1152){
    int c = (id - 1152) * 256 + threadIdx.x;
    float v = (c < 512) ? Wqb[c] : (c < 1024) ? Wkb[c-512] : (c < 1536) ? Wvb[c-1024] : Wdb[c-1536];
    biasAll[c] = v;
    return;
  }
  const float* W; int RO, N, local;
  if      (id < 256){ W = Wq; RO = 0;    N = 512; local = id; }
  else if (id < 512){ W = Wk; RO = 512;  N = 512; local = id - 256; }
  else if (id < 768){ W = Wv; RO = 1024; N = 512; local = id - 512; }
  else if (id < 896){ W = Wd; RO = 1536; N = 256; local = id - 768; }
  else              { W = Wo; RO = 1792; N = 512; local = id - 896; }
  int ntiles = N >> 5;
  int n0 = (local & (ntiles - 1)) * 32, k0 = (local / ntiles) * 32;
  float (*tile)[33] = (float(*)[33])pbuf;
  int tx = threadIdx.x & 31, ty = threadIdx.x >> 5;
  #pragma unroll
  for (int i = 0; i < 32; i += 8)
    tile[ty + i][tx] = W[(size_t)(k0 + ty + i) * N + n0 + tx];
  __syncthreads();
  #pragma unroll
  for (int i = 0; i < 32; i += 8)
    WT[(size_t)(RO + n0 + ty + i) * 512 + k0 + tx] = f2bf(tile[tx][ty + i]);
}

// ---------------- 128x128 pipelined GEMM (BK=64, 2-slot ring, 2 blocks/CU, persistent) ----------------
// MODE 0: A=Xb, B=WT[0,1792): bx 0-3 Q, 4-7 K(preLN), 8-11 V(preLN + row stats), 12-13 hs
// MODE 1: A=Cbp, B=WT[1792,2304): f32 out + bias
template<int MODE>
__global__ __launch_bounds__(256, 2) void gemmP(
    const u16* __restrict__ Abase, const u16* __restrict__ WT, const float* __restrict__ biasAll,
    u16* __restrict__ Qb, u16* __restrict__ Kb, u16* __restrict__ Vb,
    float* __restrict__ hsf, float* __restrict__ cmx, float* __restrict__ csm,
    float* __restrict__ pstatV, float* __restrict__ Cf)
{
  __shared__ __align__(16) u16 smem[32768];   // 64 KB: A[2][8192] | B[2][8192]
  const int t = threadIdx.x, lane = t & 63, w = t >> 6;
  const int wm = w >> 1, wn = w & 1;
  const int lrow = lane & 15, lk = lane >> 4;
  const u16* Bbase = (MODE == 0) ? WT : (WT + (size_t)1792*512);
  const int srow = w*32 + (lane >> 3);
  const int scol = ((lane & 7) ^ (lane >> 3)) * 8;
  const int swz = (lrow & 7);
  const int NCH = (MODE == 0) ? 1792 : 512;
  const f32x4 fz = {0.f,0.f,0.f,0.f};

  for (int ch = blockIdx.x; ch < NCH; ch += 512){
    int by, bx;
    {
      int xcd = ch & 7, c = ch >> 3;
      if (MODE == 0){ by = xcd*16 + c/14;   bx = c % 14; }
      else          { by = xcd*16 + (c>>2); bx = c & 3; }
    }
    const int m0 = by*128, n0 = bx*128;
    const u16* sA = Abase + (size_t)(m0 + srow)*512 + scol;
    const u16* sB = Bbase + (size_t)(n0 + srow)*512 + scol;

    f32x4 acc[4][4];
    #pragma unroll
    for (int i = 0; i < 4; i++)
      #pragma unroll
      for (int j = 0; j < 4; j++) acc[i][j] = fz;

    auto stage = [&](int tt){
      int slot = tt & 1;
      #pragma unroll
      for (int i = 0; i < 4; i++){
        gload16(sA + tt*64 + (size_t)i*4096, smem + slot*8192 + (w*4 + i)*512);
        gload16(sB + tt*64 + (size_t)i*4096, smem + 16384 + slot*8192 + (w*4 + i)*512);
      }
    };

    stage(0);
    stage(1);

    #pragma unroll
    for (int tt = 0; tt < 8; tt++){
      if (tt < 7) asm volatile("s_waitcnt vmcnt(8)" ::: "memory");   // tile tt landed
      else        asm volatile("s_waitcnt vmcnt(0)" ::: "memory");
      __builtin_amdgcn_s_barrier();
      const u16* aS = smem + (tt & 1)*8192;
      const u16* bS = smem + 16384 + (tt & 1)*8192;
      #pragma unroll
      for (int ks = 0; ks < 2; ks++){
        bf16x8 af[4], bfv[4];
        #pragma unroll
        for (int mi = 0; mi < 4; mi++){
          int r = wm*64 + mi*16 + lrow;
          af[mi] = *(const bf16x8*)(aS + (r*8 + ((ks*4 + lk) ^ swz))*8);
        }
        #pragma unroll
        for (int ni = 0; ni < 4; ni++){
          int r = wn*64 + ni*16 + lrow;
          bfv[ni] = *(const bf16x8*)(bS + (r*8 + ((ks*4 + lk) ^ swz))*8);
        }
        #pragma unroll
        for (int mi = 0; mi < 4; mi++)
          #pragma unroll
          for (int ni = 0; ni < 4; ni++)
            acc[mi][ni] = mfma16(bfv[ni], af[mi], acc[mi][ni]);   // C^T frags
      }
      __builtin_amdgcn_s_barrier();       // all waves done reading slot tt&1
      if (tt + 2 < 8) stage(tt + 2);      // now safe to overwrite it
    }

    // ---------------- epilogue (C^T: thread holds 4 consecutive output cols) ----------------
    if (MODE == 1){
      #pragma unroll
      for (int mi = 0; mi < 4; mi++){
        int grow = m0 + wm*64 + mi*16 + lrow;
        #pragma unroll
        for (int ni = 0; ni < 4; ni++){
          int gcol0 = n0 + wn*64 + ni*16 + lk*4;
          f32x4 bv4 = *(const f32x4*)(biasAll + gcol0);
          f32x4 vv;
          #pragma unroll
          for (int rr = 0; rr < 4; rr++) vv[rr] = acc[mi][ni][rr] + bv4[rr];
          *(f32x4*)(Cf + (size_t)grow*512 + gcol0) = vv;
        }
      }
      continue;
    }

    if (bx < 12){
      const int sel = bx >> 2;
      u16* dst = (sel == 0) ? Qb : (sel == 1) ? Kb : Vb;
      const float scale = (sel == 0) ? 0.125f : 1.0f;
      f32x4 bv4s[4];
      #pragma unroll
      for (int ni = 0; ni < 4; ni++)
        bv4s[ni] = *(const f32x4*)(biasAll + n0 + wn*64 + ni*16 + lk*4);
      #pragma unroll
      for (int mi = 0; mi < 4; mi++){
        int grow = m0 + wm*64 + mi*16 + lrow;
        int b = grow >> 13, s = grow & 8191;
        #pragma unroll
        for (int ni = 0; ni < 4; ni++){
          int gcol0 = n0 + wn*64 + ni*16 + lk*4;
          int lcol0 = gcol0 & 511, hh = lcol0 >> 6, dd0 = lcol0 & 63;
          float v0 = (acc[mi][ni][0] + bv4s[ni][0]) * scale;
          float v1 = (acc[mi][ni][1] + bv4s[ni][1]) * scale;
          float v2 = (acc[mi][ni][2] + bv4s[ni][2]) * scale;
          float v3 = (acc[mi][ni][3] + bv4s[ni][3]) * scale;
          u32* p = (u32*)(dst + (((size_t)(b*8 + hh))*8192 + s)*64 + dd0);
          p[0] = pk2(v0, v1);
          p[1] = pk2(v2, v3);
        }
      }
      if (sel == 2){
        float* vst = (float*)smem;      // [128][4] : per-wn {sum,sq}
        __syncthreads();
        #pragma unroll
        for (int mi = 0; mi < 4; mi++){
          float s = 0.f, q = 0.f;
          #pragma unroll
          for (int ni = 0; ni < 4; ni++)
            #pragma unroll
            for (int rr = 0; rr < 4; rr++){
              float v = acc[mi][ni][rr] + bv4s[ni][rr];
              s += v; q += v*v;
            }
          s += __shfl_xor(s, 16); q += __shfl_xor(q, 16);
          s += __shfl_xor(s, 32); q += __shfl_xor(q, 32);
          if (lk == 0){
            int rloc = wm*64 + mi*16 + lrow;
            vst[rloc*4 + wn*2]     = s;
            vst[rloc*4 + wn*2 + 1] = q;
          }
        }
        __syncthreads();
        if (t < 128){
          float s = vst[t*4+0] + vst[t*4+2];
          float q = vst[t*4+1] + vst[t*4+3];
          pstatV[(size_t)(m0 + t)*8 + (bx - 8)*2]     = s;
          pstatV[(size_t)(m0 + t)*8 + (bx - 8)*2 + 1] = q;
        }
      }
    } else {
      // hs: f32x4 stores + per-128-row column softmax partials (one chunk per block)
      float* pm = (float*)smem;          // [2][128]
      float* ps = pm + 256;
      __syncthreads();
      #pragma unroll
      for (int ni = 0; ni < 4; ni++){
        int gcol0 = n0 + wn*64 + ni*16 + lk*4;
        int c0 = gcol0 - 1536;
        f32x4 bv4 = *(const f32x4*)(biasAll + gcol0);
        float mx[4], sm[4];
        #pragma unroll
        for (int rr = 0; rr < 4; rr++){ mx[rr] = -1e30f; sm[rr] = 0.f; }
        #pragma unroll
        for (int mi = 0; mi < 4; mi++){
          int grow = m0 + wm*64 + mi*16 + lrow;
          f32x4 v;
          #pragma unroll
          for (int rr = 0; rr < 4; rr++){
            v[rr] = acc[mi][ni][rr] + bv4[rr];
            float nm = fmaxf(mx[rr], v[rr]);
            sm[rr] = sm[rr]*__expf(mx[rr] - nm) + __expf(v[rr] - nm);
            mx[rr] = nm;
          }
          *(f32x4*)(hsf + (size_t)grow*256 + c0) = v;
        }
        #pragma unroll
        for (int rr = 0; rr < 4; rr++){
          #pragma unroll
          for (int d2 = 1; d2 < 16; d2 <<= 1){
            float om = __shfl_xor(mx[rr], d2), os = __shfl_xor(sm[rr], d2);
            float nm = fmaxf(mx[rr], om);
            sm[rr] = sm[rr]*__expf(mx[rr] - nm) + os*__expf(om - nm);
            mx[rr] = nm;
          }
        }
        if (lrow == 0){
          int cl = wn*64 + ni*16 + lk*4;
          f32x4 m4 = {mx[0], mx[1], mx[2], mx[3]};
          f32x4 s4 = {sm[0], sm[1], sm[2], sm[3]};
          *(f32x4*)(pm + wm*128 + cl) = m4;
          *(f32x4*)(ps + wm*128 + cl) = s4;
        }
      }
      __syncthreads();
      if (t < 128){
        float ma = pm[t], mb = pm[128 + t];
        float nm = fmaxf(ma, mb);
        float s = ps[t]*__expf(ma - nm) + ps[128 + t]*__expf(mb - nm);
        int b = m0 >> 13, chunk = (m0 & 8191) >> 7;
        int c = (n0 - 1536) + t;
        cmx[((size_t)b*64 + chunk)*256 + c] = nm;
        csm[((size_t)b*64 + chunk)*256 + c] = s;
      }
    }
    __syncthreads();   // protect smem/LDS ring before next chunk's staging
  }
}

// ---------------- mid: K LN stats (0..4095) + V LN/transpose (4096..6143) + smax comb (6144..6145) ----------------
__global__ __launch_bounds__(256) void mid_kernel(
    const u16* __restrict__ Kb, float* __restrict__ kstat,
    const u16* __restrict__ Vb, const float* __restrict__ pstatV,
    const float* __restrict__ gg, const float* __restrict__ bb, u16* __restrict__ VbT,
    const float* __restrict__ cmax, const float* __restrict__ csum,
    float* __restrict__ gmax, float* __restrict__ gsum)
{
  __shared__ __align__(16) char mbuf[9216];
  const int bid = blockIdx.x;
  if (bid < 4096){
    const int lane = threadIdx.x & 63, w = threadIdx.x >> 6;
    const int row = bid * 4 + w;
    const int b = row >> 13, si = row & 8191;
    const int hh = lane >> 3, d = (lane & 7) * 8;
    const u16* p = Kb + (((size_t)(b*8 + hh))*8192 + si)*64 + d;
    bf16x8 raw = *(const bf16x8*)p;
    float x[8];
    #pragma unroll
    for (int j = 0; j < 8; j++) x[j] = bf2f((u16)raw[j]);
    float s = 0.f, q = 0.f;
    #pragma unroll
    for (int j = 0; j < 8; j++){ s += x[j]; q += x[j]*x[j]; }
    #pragma unroll
    for (int d2 = 1; d2 < 64; d2 <<= 1){ s += __shfl_xor(s, d2); q += __shfl_xor(q, d2); }
    float mean = s * (1.f/512.f);
    float var  = q * (1.f/512.f) - mean*mean;
    float rstd = rsqrtf(var + 1e-5f);
    if (lane == 0){
      kstat[(size_t)row*2]     = mean;
      kstat[(size_t)row*2 + 1] = rstd;
    }
    return;
  }
  if (bid < 6144){
    int id2 = bid - 4096;
    const int st = id2 & 127, bh = id2 >> 7;
    const int b = bh >> 3, h = bh & 7;
    const int t = threadIdx.x;
    u16 (*tile)[72] = (u16(*)[72])mbuf;
    {
      int row = t >> 2, cc = (t & 3) * 16;
      int grow = b*8192 + st*64 + row;
      f32x4 p0 = *(const f32x4*)(pstatV + (size_t)grow*8);
      f32x4 p1 = *(const f32x4*)(pstatV + (size_t)grow*8 + 4);
      float mean = (p0[0]+p0[2]+p1[0]+p1[2]) * (1.f/512.f);
      float msq  = (p0[1]+p0[3]+p1[1]+p1[3]) * (1.f/512.f);
      float rstd = rsqrtf(msq - mean*mean + 1e-5f);
      const u16* src = Vb + ((size_t)bh*8192 + st*64 + row)*64 + cc;
      bf16x8 v0 = *(const bf16x8*)src, v1 = *(const bf16x8*)(src + 8);
      #pragma unroll
      for (int j = 0; j < 8; j++){
        int c = h*64 + cc + j;
        tile[row][cc + j]     = f2bf((bf2f((u16)v0[j]) - mean)*rstd*gg[c] + bb[c]);
        int c2 = c + 8;
        tile[row][cc + 8 + j] = f2bf((bf2f((u16)v1[j]) - mean)*rstd*gg[c2] + bb[c2]);
      }
    }
    __syncthreads();
    {
      int d = t >> 2, sc4 = (t & 3) * 16;
      bf16x8 o0, o1;
      #pragma unroll
      for (int i = 0; i < 8; i++) o0[i] = (short)tile[sc4 + i][d];
      #pragma unroll
      for (int i = 0; i < 8; i++) o1[i] = (short)tile[sc4 + 8 + i][d];
      u16* dst = VbT + ((size_t)bh*64 + d)*8192 + st*64 + sc4;
      *(bf16x8*)dst       = o0;
      *(bf16x8*)(dst + 8) = o1;
    }
    return;
  }
  {
    int b = bid - 6144, c = threadIdx.x;
    float m[4], s[4];
    #pragma unroll
    for (int u = 0; u < 4; u++){ m[u] = -1e30f; s[u] = 0.f; }
    for (int ch = 0; ch < 64; ch += 4){
      #pragma unroll
      for (int u = 0; u < 4; u++){
        float cm = cmax[((size_t)b*64 + ch + u)*256 + c];
        float cs = csum[((size_t)b*64 + ch + u)*256 + c];
        float nm = fmaxf(m[u], cm);
        s[u] = s[u]*__expf(m[u] - nm) + cs*__expf(cm - nm);
        m[u] = nm;
      }
    }
    #pragma unroll
    for (int u = 1; u < 4; u++){
      float nm = fmaxf(m[0], m[u]);
      s[0] = s[0]*__expf(m[0]-nm) + s[u]*__expf(m[u]-nm);
      m[0] = nm;
    }
    gmax[b*256 + c] = m[0]; gsum[b*256 + c] = s[0];
  }
}

// ---------------- compressed K_c/V_c partial sums via MFMA (K,V LN'd on the fly) ----------------
__global__ __launch_bounds__(256) void cmp2_kernel(const float* __restrict__ hsf,
    const float* __restrict__ gmax, const float* __restrict__ gsum,
    const u16* __restrict__ Kb, const u16* __restrict__ Vb,
    const float* __restrict__ kstat, const float* __restrict__ pstatV,
    const float* __restrict__ gg, const float* __restrict__ bb,
    float* __restrict__ pK, float* __restrict__ pV)
{
  __shared__ __align__(16) u16 Pt[32*72];
  __shared__ __align__(16) u16 Kt[64*72];
  __shared__ __align__(16) u16 Vt[64*72];
  const int sch = blockIdx.x, bh = blockIdx.y;
  const int b = bh >> 3, h = bh & 7;
  const int t = threadIdx.x, lane = t & 63, w = t >> 6;
  const int lrow = lane & 15, lk = lane >> 4;
  const int sl = lane;
  float gm[8], gi[8];
  #pragma unroll
  for (int j = 0; j < 8; j++){
    int c = h*32 + w*8 + j;
    gm[j] = gmax[b*256 + c];
    gi[j] = 1.0f / gsum[b*256 + c];
  }
  float glv[16], blv[16];
  #pragma unroll
  for (int j = 0; j < 16; j++){
    int c = h*64 + w*16 + j;
    glv[j] = gg[c]; blv[j] = bb[c];
  }
  const f32x4 fz = {0.f,0.f,0.f,0.f};
  f32x4 aK[2], aV[2];
  aK[0]=fz; aK[1]=fz; aV[0]=fz; aV[1]=fz;

  for (int tile = 0; tile < 4; ++tile){
    int s0 = sch*256 + tile*64;
    int grow = b*8192 + s0 + sl;
    {
      const float* src = hsf + (size_t)grow*256 + h*32 + w*8;
      f32x4 x0 = *(const f32x4*)src, x1 = *(const f32x4*)(src + 4);
      #pragma unroll
      for (int j = 0; j < 4; j++){
        Pt[(w*8 + j)*72 + sl]     = f2bf(__expf(x0[j] - gm[j])   * gi[j]);
        Pt[(w*8 + 4 + j)*72 + sl] = f2bf(__expf(x1[j] - gm[4+j]) * gi[4+j]);
      }
    }
    {
      f32x2 st = *(const f32x2*)(kstat + (size_t)grow*2);
      const u16* ks = Kb + ((size_t)bh*8192 + s0 + sl)*64 + w*16;
      bf16x8 k0 = *(const bf16x8*)ks, k1 = *(const bf16x8*)(ks + 8);
      #pragma unroll
      for (int j = 0; j < 8; j++){
        Kt[(w*16 + j)*72 + sl]     = f2bf((bf2f((u16)k0[j]) - st[0])*st[1]*glv[j]   + blv[j]);
        Kt[(w*16 + 8 + j)*72 + sl] = f2bf((bf2f((u16)k1[j]) - st[0])*st[1]*glv[8+j] + blv[8+j]);
      }
    }
    {
      f32x4 p0 = *(const f32x4*)(pstatV + (size_t)grow*8);
      f32x4 p1 = *(const f32x4*)(pstatV + (size_t)grow*8 + 4);
      float mean = (p0[0]+p0[2]+p1[0]+p1[2]) * (1.f/512.f);
      float msq  = (p0[1]+p0[3]+p1[1]+p1[3]) * (1.f/512.f);
      float rstd = rsqrtf(msq - mean*mean + 1e-5f);
      const u16* vs = Vb + ((size_t)bh*8192 + s0 + sl)*64 + w*16;
      bf16x8 v0 = *(const bf16x8*)vs, v1 = *(const bf16x8*)(vs + 8);
      #pragma unroll
      for (int j = 0; j < 8; j++){
        Vt[(w*16 + j)*72 + sl]     = f2bf((bf2f((u16)v0[j]) - mean)*rstd*glv[j]   + blv[j]);
        Vt[(w*16 + 8 + j)*72 + sl] = f2bf((bf2f((u16)v1[j]) - mean)*rstd*glv[8+j] + blv[8+j]);
      }
    }
    __syncthreads();
    #pragma unroll
    for (int ks = 0; ks < 2; ks++){
      bf16x8 a0 = *(const bf16x8*)(Pt + (lrow)*72      + ks*32 + lk*8);
      bf16x8 a1 = *(const bf16x8*)(Pt + (16 + lrow)*72 + ks*32 + lk*8);
      bf16x8 bK = *(const bf16x8*)(Kt + (w*16 + lrow)*72 + ks*32 + lk*8);
      bf16x8 bV = *(const bf16x8*)(Vt + (w*16 + lrow)*72 + ks*32 + lk*8);
      aK[0] = mfma16(a0, bK, aK[0]);
      aK[1] = mfma16(a1, bK, aK[1]);
      aV[0] = mfma16(a0, bV, aV[0]);
      aV[1] = mfma16(a1, bV, aV[1]);
    }
    __syncthreads();
  }
  size_t base = ((size_t)bh*32 + sch)*2048;
  #pragma unroll
  for (int li = 0; li < 2; li++){
    #pragma unroll
    for (int r = 0; r < 4; r++){
      size_t o = base + (size_t)(li*16 + lk*4 + r)*64 + w*16 + lrow;
      pK[o] = aK[li][r];
      pV[o] = aV[li][r];
    }
  }
}

// ---------------- reduce partials + LN_s -> Kcb [bh][32][64], VcT [bh][64][32] ----------------
__global__ __launch_bounds__(256) void ln_c_kernel(const float* __restrict__ pK, const float* __restrict__ pV,
    const float* __restrict__ gg, const float* __restrict__ bb,
    u16* __restrict__ Kcb, u16* __restrict__ VcT)
{
  __shared__ float red[4][4];
  const int b = blockIdx.x >> 5, l = blockIdx.x & 31;
  const int t = threadIdx.x, lane = t & 63, w = t >> 6;
  float xk[2], xv[2];
  #pragma unroll
  for (int q2 = 0; q2 < 2; q2++){
    int c = t + q2*256;
    int hh = c >> 6, d = c & 63;
    float sk = 0.f, sv = 0.f;
    for (int ch = 0; ch < 32; ch++){
      size_t idx = (((size_t)(b*8 + hh)*32 + ch)*2048) + l*64 + d;
      sk += pK[idx]; sv += pV[idx];
    }
    xk[q2] = sk; xv[q2] = sv;
  }
  float s1 = xk[0]+xk[1], q1 = xk[0]*xk[0]+xk[1]*xk[1];
  float s2 = xv[0]+xv[1], q2s = xv[0]*xv[0]+xv[1]*xv[1];
  #pragma unroll
  for (int d2 = 1; d2 < 64; d2 <<= 1){
    s1 += __shfl_xor(s1, d2); q1 += __shfl_xor(q1, d2);
    s2 += __shfl_xor(s2, d2); q2s += __shfl_xor(q2s, d2);
  }
  if (lane == 0){ red[0][w]=s1; red[1][w]=q1; red[2][w]=s2; red[3][w]=q2s; }
  __syncthreads();
  s1 = red[0][0]+red[0][1]+red[0][2]+red[0][3];
  q1 = red[1][0]+red[1][1]+red[1][2]+red[1][3];
  s2 = red[2][0]+red[2][1]+red[2][2]+red[2][3];
  q2s = red[3][0]+red[3][1]+red[3][2]+red[3][3];
  float mk = s1*(1.f/512.f), vk = q1*(1.f/512.f) - mk*mk, rk = rsqrtf(vk + 1e-5f);
  float mv = s2*(1.f/512.f), vvv = q2s*(1.f/512.f) - mv*mv, rv = rsqrtf(vvv + 1e-5f);
  #pragma unroll
  for (int q2 = 0; q2 < 2; q2++){
    int c = t + q2*256;
    int hh = c >> 6, d = c & 63;
    Kcb[(((size_t)(b*8 + hh))*32 + l)*64 + d] = f2bf((xk[q2]-mk)*rk*gg[c] + bb[c]);
    VcT[(((size_t)(b*8 + hh))*64 + d)*32 + l] = f2bf((xv[q2]-mv)*rv*gg[c] + bb[c]);
  }
}

// ---------------- fused long-short attention per (b,h,g); K LN'd during staging ----------------
// XCD-aware g remap (bijective, 64 % 8 == 0).
__global__ __launch_bounds__(512, 4) void attn2_kernel(
    const u16* __restrict__ Qb, const u16* __restrict__ Kb, const u16* __restrict__ Kcb,
    const u16* __restrict__ VbT, const u16* __restrict__ VcT,
    const float* __restrict__ kstat, const float* __restrict__ lnlg, const float* __restrict__ lnlb,
    u16* __restrict__ Cb)
{
  __shared__ __align__(16) char smem[74752];
  u16* Vt = (u16*)(smem + 36864);
  u16* Pl = (u16*)smem;

  const int g = (blockIdx.x & 7) * 8 + (blockIdx.x >> 3);
  const int h = blockIdx.y, b = blockIdx.z;
  const int bh = b*8 + h;
  const int t = threadIdx.x, lane = t & 63, w = t >> 6;
  const int lrow = lane & 15, lk = lane >> 4;
  const int s0 = g*128 - 64;
  const bf16x8 bz = {0,0,0,0,0,0,0,0};
  const f32x4 fz = {0.f,0.f,0.f,0.f};

  float g8[8], b8[8];
  {
    int kcl = t & 7;
    #pragma unroll
    for (int j = 0; j < 8; j++){
      int c = h*64 + kcl*8 + j;
      g8[j] = lnlg[c]; b8[j] = lnlb[c];
    }
  }

  #pragma unroll
  for (int it = 0; it < 5; it++){
    int idx = it*512 + t;
    if (idx < 2304){
      int row = idx >> 3, kc = idx & 7;
      bf16x8 v = bz;
      if (row < 256){
        int sk = s0 + row;
        if (sk >= 0 && sk < 8192){
          v = *(const bf16x8*)(Kb + ((size_t)bh*8192 + sk)*64 + kc*8);
          f32x2 st = *(const f32x2*)(kstat + (size_t)(b*8192 + sk)*2);
          #pragma unroll
          for (int j = 0; j < 8; j++)
            v[j] = (short)f2bf((bf2f((u16)v[j]) - st[0])*st[1]*g8[j] + b8[j]);
        }
      } else {
        v = *(const bf16x8*)(Kcb + ((size_t)bh*32 + (row - 256))*64 + kc*8);
      }
      int off = row*128 + kc*16; off ^= (row & 7) << 4;
      *(bf16x8*)(smem + off) = v;
    }
  }
  #pragma unroll
  for (int it = 0; it < 4; it++){
    int idx = it*512 + t;
    int d = idx >> 5, cc = idx & 31;
    int sk = s0 + cc*8;
    bf16x8 v = bz;
    if (sk >= 0 && sk < 8192) v = *(const bf16x8*)(VbT + ((size_t)bh*64 + d)*8192 + sk);
    *(bf16x8*)(Vt + d*296 + cc*8) = v;
  }
  if (t < 256){
    int d = t >> 2, cc = t & 3;
    bf16x8 v = *(const bf16x8*)(VcT + ((size_t)bh*64 + d)*32 + cc*8);
    *(bf16x8*)(Vt + d*296 + 256 + cc*8) = v;
  }
  bf16x8 qf[2];
  #pragma unroll
  for (int ks = 0; ks < 2; ks++)
    qf[ks] = *(const bf16x8*)(Qb + ((size_t)bh*8192 + g*128 + w*16 + lrow)*64 + ks*32 + lk*8);

  __syncthreads();

  f32x4 sc[18];
  #pragma unroll
  for (int j = 0; j < 18; j++) sc[j] = fz;
  __builtin_amdgcn_s_setprio(1);
  #pragma unroll
  for (int j = 0; j < 18; j++){
    int row = j*16 + lrow;
    #pragma unroll
    for (int ks = 0; ks < 2; ks++){
      int off = row*128 + ks*64 + lk*16; off ^= (row & 7) << 4;
      bf16x8 kf = *(const bf16x8*)(smem + off);
      sc[j] = mfma16(kf, qf[ks], sc[j]);
    }
  }
  __builtin_amdgcn_s_setprio(0);

  #pragma unroll
  for (int j = 0; j < 16; j++){
    int sb = s0 + j*16 + lk*4;
    if (sb < 0 || sb >= 8192){
      sc[j][0] = -1e30f; sc[j][1] = -1e30f; sc[j][2] = -1e30f; sc[j][3] = -1e30f;
    }
  }

  float m = -1e30f;
  #pragma unroll
  for (int j = 0; j < 18; j++)
    m = fmaxf(m, fmaxf(fmaxf(sc[j][0], sc[j][1]), fmaxf(sc[j][2], sc[j][3])));
  m = fmaxf(m, __shfl_xor(m, 16));
  m = fmaxf(m, __shfl_xor(m, 32));
  float ssum = 0.f;
  #pragma unroll
  for (int j = 0; j < 18; j++){
    #pragma unroll
    for (int r = 0; r < 4; r++){
      float e = __expf(sc[j][r] - m);
      sc[j][r] = e; ssum += e;
    }
  }
  ssum += __shfl_xor(ssum, 16);
  ssum += __shfl_xor(ssum, 32);
  float inv = 1.0f / ssum;

  f32x4 ao[4];
  #pragma unroll
  for (int nj = 0; nj < 4; nj++) ao[nj] = fz;
  const int prow = w*16 + lrow;

  #pragma unroll
  for (int c = 0; c < 3; c++){
    __syncthreads();
    #pragma unroll
    for (int jj = 0; jj < 6; jj++){
      int j = c*6 + jj;
      u32* dst = (u32*)(Pl + prow*104 + jj*16 + lk*4);
      dst[0] = pk2(sc[j][0], sc[j][1]);
      dst[1] = pk2(sc[j][2], sc[j][3]);
    }
    __syncthreads();
    __builtin_amdgcn_s_setprio(1);
    #pragma unroll
    for (int ksl = 0; ksl < 3; ksl++){
      bf16x8 pb = *(const bf16x8*)(Pl + prow*104 + ksl*32 + lk*8);
      #pragma unroll
      for (int nj = 0; nj < 4; nj++){
        bf16x8 av = *(const bf16x8*)(Vt + (nj*16 + lrow)*296 + c*96 + ksl*32 + lk*8);
        ao[nj] = mfma16(av, pb, ao[nj]);
      }
    }
    __builtin_amdgcn_s_setprio(0);
  }

  const int qglob = g*128 + w*16 + lrow;
  #pragma unroll
  for (int nj = 0; nj < 4; nj++){
    u32* dst = (u32*)(Cb + ((size_t)b*8192 + qglob)*512 + h*64 + nj*16 + lk*4);
    dst[0] = pk2(ao[nj][0]*inv, ao[nj][1]*inv);
    dst[1] = pk2(ao[nj][2]*inv, ao[nj][3]*inv);
  }
}

// ---------------- workspace layout ----------------
constexpr size_t OFF_XB   = 0;
constexpr size_t OFF_WT   = OFF_XB  + 16777216;
constexpr size_t OFF_QB   = OFF_WT  + 2359296;
constexpr size_t OFF_KB   = OFF_QB  + 16777216;
constexpr size_t OFF_VB   = OFF_KB  + 16777216;
constexpr size_t OFF_CB   = OFF_VB  + 16777216;
constexpr size_t OFF_VBT  = OFF_CB  + 16777216;
constexpr size_t OFF_HSF  = OFF_VBT + 16777216;
constexpr size_t OFF_CMX  = OFF_HSF + 16777216;
constexpr size_t OFF_CSM  = OFF_CMX + 131072;
constexpr size_t OFF_GMX  = OFF_CSM + 131072;
constexpr size_t OFF_GSM  = OFF_GMX + 2048;
constexpr size_t OFF_PK   = OFF_GSM + 2048;
constexpr size_t OFF_PV   = OFF_PK  + 4194304;
constexpr size_t OFF_KCB  = OFF_PV  + 4194304;
constexpr size_t OFF_VCT  = OFF_KCB + 65536;
constexpr size_t OFF_BIAS = OFF_VCT + 65536;
constexpr size_t OFF_PSV  = OFF_BIAS + 8192;          // 16384*8*4 = 524288
constexpr size_t OFF_KST  = OFF_PSV + 524288;         // 16384*2*4 = 131072

extern "C" void kernel_launch(void* const* d_in, const int* in_sizes, int n_in,
                              void* d_out, int out_size, void* d_ws, size_t ws_size,
                              hipStream_t stream)
{
  const float* X    = (const float*)d_in[0];
  const float* Wq   = (const float*)d_in[2];
  const float* Wqb  = (const float*)d_in[3];
  const float* Wk   = (const float*)d_in[4];
  const float* Wkb  = (const float*)d_in[5];
  const float* Wv   = (const float*)d_in[6];
  const float* Wvb  = (const float*)d_in[7];
  const float* Wo   = (const float*)d_in[8];
  const float* Wob  = (const float*)d_in[9];
  const float* lnlg = (const float*)d_in[10];
  const float* lnlb = (const float*)d_in[11];
  const float* lnsg = (const float*)d_in[12];
  const float* lnsb = (const float*)d_in[13];
  const float* Wd   = (const float*)d_in[14];
  const float* Wdb  = (const float*)d_in[15];
  float* out = (float*)d_out;

  char* ws = (char*)d_ws;
  u16*   Xb   = (u16*)(ws + OFF_XB);
  u16*   WT   = (u16*)(ws + OFF_WT);
  u16*   Qb   = (u16*)(ws + OFF_QB);
  u16*   Kb   = (u16*)(ws + OFF_KB);
  u16*   Vb   = (u16*)(ws + OFF_VB);
  u16*   Cbp  = (u16*)(ws + OFF_CB);
  u16*   VbT  = (u16*)(ws + OFF_VBT);
  float* hsf  = (float*)(ws + OFF_HSF);
  float* cmx  = (float*)(ws + OFF_CMX);
  float* csm  = (float*)(ws + OFF_CSM);
  float* gmx  = (float*)(ws + OFF_GMX);
  float* gsm  = (float*)(ws + OFF_GSM);
  float* pK   = (float*)(ws + OFF_PK);
  float* pV   = (float*)(ws + OFF_PV);
  u16*   Kcb  = (u16*)(ws + OFF_KCB);
  u16*   VcT  = (u16*)(ws + OFF_VCT);
  float* biasAll = (float*)(ws + OFF_BIAS);
  float* pstatV  = (float*)(ws + OFF_PSV);
  float* kstat   = (float*)(ws + OFF_KST);

  prep_kernel<<<dim3(5255), dim3(256), 0, stream>>>(X, Xb, Wq, Wk, Wv, Wd, Wo,
                                                    Wqb, Wkb, Wvb, Wdb, WT, biasAll);

  gemmP<0><<<dim3(512), dim3(256), 0, stream>>>(Xb, WT, biasAll, Qb, Kb, Vb,
                                                hsf, cmx, csm, pstatV, nullptr);

  mid_kernel<<<dim3(6146), dim3(256), 0, stream>>>(Kb, kstat, Vb, pstatV, lnlg, lnlb, VbT,
                                                   cmx, csm, gmx, gsm);

  cmp2_kernel<<<dim3(32,16), dim3(256), 0, stream>>>(hsf, gmx, gsm, Kb, Vb, kstat, pstatV,
                                                     lnlg, lnlb, pK, pV);
  ln_c_kernel<<<dim3(64), dim3(256), 0, stream>>>(pK, pV, lnsg, lnsb, Kcb, VcT);

  attn2_kernel<<<dim3(64,8,2), dim3(512), 0, stream>>>(Qb, Kb, Kcb, VbT, VcT,
                                                       kstat, lnlg, lnlb, Cbp);

  gemmP<1><<<dim3(512), dim3(256), 0, stream>>>(Cbp, WT, Wob, nullptr, nullptr, nullptr,
                                                nullptr, nullptr, nullptr, nullptr, out);
}